// Round 1
// baseline (620.966 us; speedup 1.0000x reference)
//
#include <hip/hip_runtime.h>
#include <float.h>

#define N_ROWS   131072
#define DIM      64
#define NCODES   1024
#define KC       128     // codes per LDS chunk
#define MTILE    128     // rows per block
#define RPT      8       // rows per thread
#define CPT      8       // codes per thread per chunk
#define XP       68      // padded LDS pitch in floats (16B-aligned rows, conflict-free)

// ws layout (bytes):
// [0,     4096)  float hnorm[1024]   0.5*||e_k||^2
// [4096,  8192)  int   counts[1024]  histogram
// [8192, 12288)  float ssePart[1024] per-block SSE partials

__global__ void vq_prep(const float* __restrict__ emb, float* __restrict__ hnorm,
                        int* __restrict__ counts) {
    int k = blockIdx.x * blockDim.x + threadIdx.x;
    if (k < NCODES) {
        float s = 0.f;
        const float* e = emb + (size_t)k * DIM;
        #pragma unroll
        for (int d = 0; d < DIM; ++d) s += e[d] * e[d];
        hnorm[k] = 0.5f * s;
        counts[k] = 0;
    }
}

__device__ inline double dist_f64(const float* __restrict__ xrow, const float* __restrict__ e) {
    double dot = 0.0, nn = 0.0;
    #pragma unroll
    for (int d = 0; d < DIM; ++d) {
        double ev = (double)e[d];
        dot += (double)xrow[d] * ev;
        nn  += ev * ev;
    }
    return 0.5 * nn - dot;
}

__global__ __launch_bounds__(256) void vq_main(
        const float* __restrict__ x, const float* __restrict__ emb,
        const float* __restrict__ hnorm, float* __restrict__ out,
        int* __restrict__ counts, float* __restrict__ ssePart) {

    __shared__ __align__(16) float xs[MTILE][XP];
    __shared__ __align__(16) float es[KC][XP];
    __shared__ float hn[KC];
    __shared__ int   rowIdx[MTILE];
    __shared__ float wred[4];

    const int tid = threadIdx.x;
    const int tx = tid & 15;   // code-group lane
    const int ty = tid >> 4;   // row-group lane
    const int rowBase = blockIdx.x * MTILE;

    // ---- stage x tile (coalesced float4) ----
    for (int f = tid; f < MTILE * 16; f += 256) {
        int r = f >> 4, d4 = f & 15;
        float4 v = ((const float4*)x)[(size_t)(rowBase + r) * 16 + d4];
        *(float4*)&xs[r][d4 * 4] = v;
    }

    float b1[RPT], b2[RPT];
    int   i1[RPT], i2[RPT];
    #pragma unroll
    for (int r = 0; r < RPT; ++r) { b1[r] = FLT_MAX; b2[r] = FLT_MAX; i1[r] = 0; i2[r] = 0; }

    for (int chunk = 0; chunk < NCODES / KC; ++chunk) {
        const int cBase = chunk * KC;
        __syncthreads();   // previous chunk fully consumed
        for (int f = tid; f < KC * 16; f += 256) {
            int c = f >> 4, d4 = f & 15;
            float4 v = ((const float4*)emb)[(size_t)(cBase + c) * 16 + d4];
            *(float4*)&es[c][d4 * 4] = v;
        }
        if (tid < KC) hn[tid] = hnorm[cBase + tid];
        __syncthreads();

        float acc[RPT][CPT];
        #pragma unroll
        for (int r = 0; r < RPT; ++r)
            #pragma unroll
            for (int c = 0; c < CPT; ++c) acc[r][c] = 0.f;

        for (int d4 = 0; d4 < 16; ++d4) {
            float4 ef[CPT];
            #pragma unroll
            for (int cc = 0; cc < CPT; ++cc)
                ef[cc] = *(const float4*)&es[cc * 16 + tx][d4 * 4];
            #pragma unroll
            for (int r = 0; r < RPT; ++r) {
                float4 xf = *(const float4*)&xs[r * 16 + ty][d4 * 4];
                #pragma unroll
                for (int cc = 0; cc < CPT; ++cc) {
                    acc[r][cc] += xf.x * ef[cc].x;
                    acc[r][cc] += xf.y * ef[cc].y;
                    acc[r][cc] += xf.z * ef[cc].z;
                    acc[r][cc] += xf.w * ef[cc].w;
                }
            }
        }

        // top-2 update (codes ascend within thread -> strict < keeps first occurrence)
        #pragma unroll
        for (int cc = 0; cc < CPT; ++cc) {
            int c = cBase + cc * 16 + tx;
            float h = hn[cc * 16 + tx];
            #pragma unroll
            for (int r = 0; r < RPT; ++r) {
                float dist = h - acc[r][cc];
                if (dist < b1[r] || (dist == b1[r] && c < i1[r])) {
                    b2[r] = b1[r]; i2[r] = i1[r];
                    b1[r] = dist;  i1[r] = c;
                } else if (dist < b2[r] || (dist == b2[r] && c < i2[r])) {
                    b2[r] = dist; i2[r] = c;
                }
            }
        }
    }

    // ---- cross-lane top-2 merge within each 16-lane tx-group ----
    #pragma unroll
    for (int r = 0; r < RPT; ++r) {
        float d1 = b1[r], d2 = b2[r];
        int j1 = i1[r], j2 = i2[r];
        #pragma unroll
        for (int m = 1; m < 16; m <<= 1) {
            float od1 = __shfl_xor(d1, m);
            float od2 = __shfl_xor(d2, m);
            int   oj1 = __shfl_xor(j1, m);
            int   oj2 = __shfl_xor(j2, m);
            bool oW = (od1 < d1) || (od1 == d1 && oj1 < j1);
            float w1 = oW ? od1 : d1;  int wi1 = oW ? oj1 : j1;  // merged best
            float l1 = oW ? d1 : od1;  int li1 = oW ? j1 : oj1;  // loser's best
            float w2 = oW ? od2 : d2;  int wi2 = oW ? oj2 : j2;  // winner's 2nd
            bool sW = (w2 < l1) || (w2 == l1 && wi2 < li1);
            d1 = w1; j1 = wi1;
            d2 = sW ? w2 : l1;
            j2 = sW ? wi2 : li1;
        }
        if (tx == 0) {
            int row = r * 16 + ty;
            int winner = j1;
            if (d2 - d1 < 1e-5f) {   // near-tie: re-rank the two candidates in fp64
                double s1 = dist_f64(&xs[row][0], emb + (size_t)j1 * DIM);
                double s2 = dist_f64(&xs[row][0], emb + (size_t)j2 * DIM);
                if (s2 < s1 || (s2 == s1 && j2 < j1)) winner = j2;
            }
            rowIdx[row] = winner;
        }
    }
    __syncthreads();

    // ---- fused epilogue: gather, straight-through output, SSE, histogram ----
    float myss = 0.f;
    for (int f = tid; f < MTILE * 16; f += 256) {
        int r = f >> 4, d4 = f & 15;
        int idx = rowIdx[r];
        float4 q  = ((const float4*)emb)[(size_t)idx * 16 + d4];
        float4 xv = *(const float4*)&xs[r][d4 * 4];
        float4 o;
        o.x = xv.x + (q.x - xv.x);
        o.y = xv.y + (q.y - xv.y);
        o.z = xv.z + (q.z - xv.z);
        o.w = xv.w + (q.w - xv.w);
        ((float4*)out)[(size_t)(rowBase + r) * 16 + d4] = o;
        float gx = o.x - xv.x, gy = o.y - xv.y, gz = o.z - xv.z, gw = o.w - xv.w;
        myss += gx * gx + gy * gy + gz * gz + gw * gw;
    }
    if (tid < MTILE) atomicAdd(&counts[rowIdx[tid]], 1);

    #pragma unroll
    for (int m = 32; m >= 1; m >>= 1) myss += __shfl_down(myss, m);
    if ((tid & 63) == 0) wred[tid >> 6] = myss;
    __syncthreads();
    if (tid == 0)
        ssePart[blockIdx.x] = wred[0] + wred[1] + wred[2] + wred[3];  // deterministic
}

__global__ void vq_final(const int* __restrict__ counts, const float* __restrict__ ssePart,
                         float* __restrict__ out) {
    __shared__ float pe[16], ps[16];
    int k = threadIdx.x;   // 1024 threads
    float p = (float)counts[k] * (1.0f / (float)N_ROWS);
    float ent = p * logf(p + 1e-10f);
    float sp = ssePart[k];
    #pragma unroll
    for (int m = 32; m >= 1; m >>= 1) {
        ent += __shfl_down(ent, m);
        sp  += __shfl_down(sp, m);
    }
    if ((k & 63) == 0) { pe[k >> 6] = ent; ps[k >> 6] = sp; }
    __syncthreads();
    if (k == 0) {
        float es = 0.f, ss = 0.f;
        #pragma unroll
        for (int w = 0; w < 16; ++w) { es += pe[w]; ss += ps[w]; }
        out[(size_t)N_ROWS * DIM]     = 1.25f * (ss / (float)(N_ROWS * DIM)); // q_loss + 0.25*e_loss
        out[(size_t)N_ROWS * DIM + 1] = expf(-es);
    }
}

extern "C" void kernel_launch(void* const* d_in, const int* in_sizes, int n_in,
                              void* d_out, int out_size, void* d_ws, size_t ws_size,
                              hipStream_t stream) {
    const float* x   = (const float*)d_in[0];
    const float* emb = (const float*)d_in[1];
    float* out    = (float*)d_out;
    float* hnorm  = (float*)d_ws;
    int*   counts = (int*)((char*)d_ws + 4096);
    float* ssePrt = (float*)((char*)d_ws + 8192);

    vq_prep<<<4, 256, 0, stream>>>(emb, hnorm, counts);
    vq_main<<<N_ROWS / MTILE, 256, 0, stream>>>(x, emb, hnorm, out, counts, ssePrt);
    vq_final<<<1, 1024, 0, stream>>>(counts, ssePrt, out);
}

// Round 2
// 168.331 us; speedup vs baseline: 3.6890x; 3.6890x over previous
//
#include <hip/hip_runtime.h>
#include <float.h>

#define N_ROWS   131072
#define DIM      64
#define NCODES   1024
#define KC       64      // codes per chunk
#define MB       64      // rows per block
#define NCHUNK   (NCODES / KC)
#define TAU      1e-5f

typedef __attribute__((ext_vector_type(8))) short short8;
typedef __attribute__((ext_vector_type(4))) float floatx4;

// ws layout: [0,4096) hnorm f32[1024]; [4096,8192) counts i32[1024]; [8192,16384) ssePart f32[2048]

__device__ inline ushort f2bf(float f) {
    uint u = __float_as_uint(f);
    return (ushort)((u + 0x7FFFu + ((u >> 16) & 1u)) >> 16);   // RTNE
}
__device__ inline float bf2f(ushort s) { return __uint_as_float(((uint)s) << 16); }

// XOR swizzle within a 128B row: spreads 16 strided lanes over 8 16B slots (G4/T2)
__device__ inline uint swz(uint row, uint b) { return row * 128u + (b ^ ((row & 7u) << 4)); }

__global__ void vq_prep(const float* __restrict__ emb, float* __restrict__ hnorm,
                        int* __restrict__ counts) {
    int k = blockIdx.x * blockDim.x + threadIdx.x;
    if (k < NCODES) {
        float s = 0.f;
        const float* e = emb + (size_t)k * DIM;
        #pragma unroll
        for (int d = 0; d < DIM; ++d) s += e[d] * e[d];
        hnorm[k] = 0.5f * s;
        counts[k] = 0;
    }
}

__device__ inline double dist64(const float* __restrict__ xr, const float* __restrict__ e) {
    double dot = 0.0, nn = 0.0;
    #pragma unroll
    for (int d = 0; d < DIM; ++d) {
        double ev = (double)e[d];
        dot += (double)xr[d] * ev;
        nn  += ev * ev;
    }
    return 0.5 * nn - dot;
}

__global__ __launch_bounds__(256, 2) void vq_main(
        const float* __restrict__ x, const float* __restrict__ emb,
        const float* __restrict__ hnorm, float* __restrict__ out,
        int* __restrict__ counts, float* __restrict__ ssePart) {

    __shared__ __align__(16) ushort xs[2][MB][DIM];   // [hi/lo][row][d], swizzled bytes
    __shared__ __align__(16) ushort es[2][KC][DIM];
    __shared__ float  h_s[KC];
    __shared__ float4 part[MB][4];
    __shared__ int    rowIdx[MB];
    __shared__ float  wred[4];

    const int tid = threadIdx.x;
    const int lane = tid & 63;
    const int w = tid >> 6;            // wave 0..3 (each wave: all 64 rows, 16 codes of chunk)
    const int cB = w * 16;
    const int l15 = lane & 15, lhi = lane >> 4;
    const int rowBase = blockIdx.x * MB;

    char* xh = (char*)&xs[0][0][0];
    char* xl = (char*)&xs[1][0][0];
    char* eh = (char*)&es[0][0][0];
    char* el = (char*)&es[1][0][0];

    // ---- stage x tile and e-chunk 0 (global f32 -> regs -> bf16 hi/lo, swizzled) ----
    float4 rx[4], re[4];
    #pragma unroll
    for (int i = 0; i < 4; ++i) {
        int f = tid + 256 * i;
        rx[i] = ((const float4*)x)[(size_t)(rowBase + (f >> 4)) * 16 + (f & 15)];
        re[i] = ((const float4*)emb)[(size_t)(f >> 4) * 16 + (f & 15)];
    }
    #pragma unroll
    for (int i = 0; i < 4; ++i) {
        int f = tid + 256 * i; int r = f >> 4, d4 = f & 15;
        float v[4] = {rx[i].x, rx[i].y, rx[i].z, rx[i].w};
        float e4[4] = {re[i].x, re[i].y, re[i].z, re[i].w};
        ushort hx[4], lx[4], he[4], le[4];
        #pragma unroll
        for (int j = 0; j < 4; ++j) {
            hx[j] = f2bf(v[j]);  lx[j] = f2bf(v[j] - bf2f(hx[j]));
            he[j] = f2bf(e4[j]); le[j] = f2bf(e4[j] - bf2f(he[j]));
        }
        uint b = swz((uint)r, (uint)d4 * 8u);
        *(ushort4*)(xh + b) = make_ushort4(hx[0], hx[1], hx[2], hx[3]);
        *(ushort4*)(xl + b) = make_ushort4(lx[0], lx[1], lx[2], lx[3]);
        *(ushort4*)(eh + b) = make_ushort4(he[0], he[1], he[2], he[3]);
        *(ushort4*)(el + b) = make_ushort4(le[0], le[1], le[2], le[3]);
    }
    if (tid < KC) h_s[tid] = hnorm[tid];
    __syncthreads();

    // ---- A fragments register-resident: [hi/lo][rm][ks] ----
    short8 afr[2][4][2];
    #pragma unroll
    for (int rm = 0; rm < 4; ++rm)
        #pragma unroll
        for (int ks = 0; ks < 2; ++ks) {
            uint b = swz((uint)(rm * 16 + l15), (uint)(ks * 64 + lhi * 16));
            afr[0][rm][ks] = *(const short8*)(xh + b);
            afr[1][rm][ks] = *(const short8*)(xl + b);
        }

    float b1[16], b2[16];
    int   i1[16], i2[16];
    #pragma unroll
    for (int s = 0; s < 16; ++s) { b1[s] = FLT_MAX; b2[s] = FLT_MAX; i1[s] = 0; i2[s] = 0; }

    for (int c = 0; c < NCHUNK; ++c) {
        // T14: issue next chunk's global loads before compute
        if (c + 1 < NCHUNK) {
            #pragma unroll
            for (int i = 0; i < 4; ++i) {
                int f = tid + 256 * i;
                re[i] = ((const float4*)emb)[(size_t)((c + 1) * KC + (f >> 4)) * 16 + (f & 15)];
            }
        }

        const float hv = h_s[cB + l15];
        const int   code = c * KC + cB + l15;
        floatx4 acc[4];
        #pragma unroll
        for (int rm = 0; rm < 4; ++rm) acc[rm] = (floatx4){0.f, 0.f, 0.f, 0.f};

        #pragma unroll
        for (int ks = 0; ks < 2; ++ks) {
            uint bb = swz((uint)(cB + l15), (uint)(ks * 64 + lhi * 16));
            short8 bh = *(const short8*)(eh + bb);
            short8 bl = *(const short8*)(el + bb);
            #pragma unroll
            for (int rm = 0; rm < 4; ++rm) {
                acc[rm] = __builtin_amdgcn_mfma_f32_16x16x32_bf16(afr[0][rm][ks], bh, acc[rm], 0, 0, 0);
                acc[rm] = __builtin_amdgcn_mfma_f32_16x16x32_bf16(afr[0][rm][ks], bl, acc[rm], 0, 0, 0);
                acc[rm] = __builtin_amdgcn_mfma_f32_16x16x32_bf16(afr[1][rm][ks], bh, acc[rm], 0, 0, 0);
            }
        }

        // top-2 update (codes strictly ascend per lane across chunks)
        #pragma unroll
        for (int rm = 0; rm < 4; ++rm)
            #pragma unroll
            for (int j = 0; j < 4; ++j) {
                float dist = hv - acc[rm][j];
                int s = rm * 4 + j;
                bool c1 = dist < b1[s];
                bool c2 = dist < b2[s];
                b2[s] = c1 ? b1[s] : (c2 ? dist : b2[s]);
                i2[s] = c1 ? i1[s] : (c2 ? code : i2[s]);
                b1[s] = c1 ? dist : b1[s];
                i1[s] = c1 ? code : i1[s];
            }

        __syncthreads();    // all waves done reading es(c)
        if (c + 1 < NCHUNK) {
            #pragma unroll
            for (int i = 0; i < 4; ++i) {
                int f = tid + 256 * i; int r = f >> 4, d4 = f & 15;
                float e4[4] = {re[i].x, re[i].y, re[i].z, re[i].w};
                ushort he[4], le[4];
                #pragma unroll
                for (int j = 0; j < 4; ++j) {
                    he[j] = f2bf(e4[j]); le[j] = f2bf(e4[j] - bf2f(he[j]));
                }
                uint b = swz((uint)r, (uint)d4 * 8u);
                *(ushort4*)(eh + b) = make_ushort4(he[0], he[1], he[2], he[3]);
                *(ushort4*)(el + b) = make_ushort4(le[0], le[1], le[2], le[3]);
            }
            if (tid < KC) h_s[tid] = hnorm[(c + 1) * KC + tid];
        }
        __syncthreads();
    }

    // ---- cross-lane top-2 merge within each 16-lane group (lanes share rows) ----
    #pragma unroll
    for (int s = 0; s < 16; ++s) {
        float d1 = b1[s], d2 = b2[s];
        int j1 = i1[s], j2 = i2[s];
        #pragma unroll
        for (int m = 1; m < 16; m <<= 1) {
            float od1 = __shfl_xor(d1, m), od2 = __shfl_xor(d2, m);
            int   oj1 = __shfl_xor(j1, m), oj2 = __shfl_xor(j2, m);
            bool oW = (od1 < d1) || (od1 == d1 && oj1 < j1);
            float w1 = oW ? od1 : d1;  int wi1 = oW ? oj1 : j1;
            float L1 = oW ? d1 : od1;  int Li1 = oW ? j1 : oj1;
            float w2 = oW ? od2 : d2;  int wi2 = oW ? oj2 : j2;
            bool sW = (w2 < L1) || (w2 == L1 && wi2 < Li1);
            d1 = w1; j1 = wi1;
            d2 = sW ? w2 : L1; j2 = sW ? wi2 : Li1;
        }
        if (l15 == 0) {
            int row = (s >> 2) * 16 + lhi * 4 + (s & 3);
            part[row][w] = make_float4(d1, __int_as_float(j1), d2, __int_as_float(j2));
        }
    }
    __syncthreads();

    // ---- per-row merge of 4 wave-partials + fp64 near-tie refine ----
    if (tid < MB) {
        float4 p = part[tid][0];
        float m1 = p.x, m2 = p.z;
        int j1 = __float_as_int(p.y), j2 = __float_as_int(p.w);
        #pragma unroll
        for (int g = 1; g < 4; ++g) {
            float4 q = part[tid][g];
            float a1 = q.x, a2 = q.z;
            int k1 = __float_as_int(q.y), k2 = __float_as_int(q.w);
            if (a1 < m1 || (a1 == m1 && k1 < j1)) {
                bool t = (a2 < m1) || (a2 == m1 && k2 < j1);
                m2 = t ? a2 : m1; j2 = t ? k2 : j1;
                m1 = a1; j1 = k1;
            } else if (a1 < m2 || (a1 == m2 && k1 < j2)) {
                m2 = a1; j2 = k1;
            }
        }
        int winner = j1;
        if (m2 - m1 < TAU) {
            const float* xr = x + (size_t)(rowBase + tid) * DIM;
            double s1 = dist64(xr, emb + (size_t)j1 * DIM);
            double s2 = dist64(xr, emb + (size_t)j2 * DIM);
            if (s2 < s1 || (s2 == s1 && j2 < j1)) winner = j2;
        }
        rowIdx[tid] = winner;
        atomicAdd(&counts[winner], 1);
    }
    __syncthreads();

    // ---- epilogue: gather, straight-through output, SSE partial ----
    float myss = 0.f;
    #pragma unroll
    for (int i = 0; i < 4; ++i) {
        int f = tid + 256 * i; int r = f >> 4, d4 = f & 15;
        int idx = rowIdx[r];
        float4 q = ((const float4*)emb)[(size_t)idx * 16 + d4];
        uint b = swz((uint)r, (uint)d4 * 8u);
        ushort4 h4 = *(ushort4*)(xh + b);
        ushort4 l4 = *(ushort4*)(xl + b);
        float xv[4] = {bf2f(h4.x) + bf2f(l4.x), bf2f(h4.y) + bf2f(l4.y),
                       bf2f(h4.z) + bf2f(l4.z), bf2f(h4.w) + bf2f(l4.w)};
        float qq[4] = {q.x, q.y, q.z, q.w};
        float o[4];
        #pragma unroll
        for (int j = 0; j < 4; ++j) {
            o[j] = xv[j] + (qq[j] - xv[j]);
            float g = o[j] - xv[j];
            myss += g * g;
        }
        ((float4*)out)[(size_t)(rowBase + r) * 16 + d4] = make_float4(o[0], o[1], o[2], o[3]);
    }
    #pragma unroll
    for (int m = 32; m >= 1; m >>= 1) myss += __shfl_down(myss, m);
    if (lane == 0) wred[w] = myss;
    __syncthreads();
    if (tid == 0)
        ssePart[blockIdx.x] = wred[0] + wred[1] + wred[2] + wred[3];
}

__global__ void vq_final(const int* __restrict__ counts, const float* __restrict__ ssePart,
                         float* __restrict__ out) {
    __shared__ float pe[16], ps[16];
    int k = threadIdx.x;   // 1024 threads
    float p = (float)counts[k] * (1.0f / (float)N_ROWS);
    float ent = p * logf(p + 1e-10f);
    float sp = ssePart[k] + ssePart[k + 1024];
    #pragma unroll
    for (int m = 32; m >= 1; m >>= 1) {
        ent += __shfl_down(ent, m);
        sp  += __shfl_down(sp, m);
    }
    if ((k & 63) == 0) { pe[k >> 6] = ent; ps[k >> 6] = sp; }
    __syncthreads();
    if (k == 0) {
        float es = 0.f, ss = 0.f;
        #pragma unroll
        for (int w = 0; w < 16; ++w) { es += pe[w]; ss += ps[w]; }
        out[(size_t)N_ROWS * DIM]     = 1.25f * (ss / (float)(N_ROWS * DIM));
        out[(size_t)N_ROWS * DIM + 1] = expf(-es);
    }
}

extern "C" void kernel_launch(void* const* d_in, const int* in_sizes, int n_in,
                              void* d_out, int out_size, void* d_ws, size_t ws_size,
                              hipStream_t stream) {
    const float* x   = (const float*)d_in[0];
    const float* emb = (const float*)d_in[1];
    float* out    = (float*)d_out;
    float* hnorm  = (float*)d_ws;
    int*   counts = (int*)((char*)d_ws + 4096);
    float* ssePrt = (float*)((char*)d_ws + 8192);

    vq_prep<<<4, 256, 0, stream>>>(emb, hnorm, counts);
    vq_main<<<N_ROWS / MB, 256, 0, stream>>>(x, emb, hnorm, out, counts, ssePrt);
    vq_final<<<1, 1024, 0, stream>>>(counts, ssePrt, out);
}

// Round 3
// 90.592 us; speedup vs baseline: 6.8545x; 1.8581x over previous
//
#include <hip/hip_runtime.h>
#include <float.h>

#define N_ROWS   131072
#define DIM      64
#define NCODES   1024
#define MB       64      // rows per block
#define NCHUNK   16      // 64 codes per chunk

typedef __attribute__((ext_vector_type(8))) short short8;
typedef __attribute__((ext_vector_type(4))) float floatx4;

// ws layout (bytes):
// [0,     4096)   nh     f32[1024]   -0.5*||e_k||^2
// [4096,  8192)   counts i32[1024]
// [8192, 16384)   ssePart f32[2048]
// [16384, 278528) blob: per (chunk c, wave w, lane l) 64B =
//                 {ehi ks0, ehi ks1, elo ks0, elo ks1} 16B fragments

__device__ inline ushort f2bf(float f) {
    uint u = __float_as_uint(f);
    return (ushort)((u + 0x7FFFu + ((u >> 16) & 1u)) >> 16);   // RTNE
}
__device__ inline float bf2f(ushort s) { return __uint_as_float(((uint)s) << 16); }

// XOR swizzle within a 128B row (T2/G4): kills 16-lane same-column bank conflicts
__device__ inline uint swz(uint row, uint b) { return row * 128u + (b ^ ((row & 7u) << 4)); }

__global__ void vq_prep(const float* __restrict__ emb, float* __restrict__ nh,
                        int* __restrict__ counts, ushort* __restrict__ blob) {
    int g = blockIdx.x * 256 + threadIdx.x;     // 0..4095 == (c*4+w)*64+l
    int l = g & 63;
    int l15 = l & 15, lhi = l >> 4;
    int c = g >> 8, w = (g >> 6) & 3;
    int code = c * 64 + w * 16 + l15;
    int k0 = lhi * 8;
    const float* er = emb + (size_t)code * DIM;

    ushort h0[8], h1[8], l0[8], l1[8];
    #pragma unroll
    for (int j = 0; j < 8; ++j) {
        float a = er[k0 + j], b = er[32 + k0 + j];
        h0[j] = f2bf(a); l0[j] = f2bf(a - bf2f(h0[j]));
        h1[j] = f2bf(b); l1[j] = f2bf(b - bf2f(h1[j]));
    }
    ushort* dst = blob + (size_t)g * 32;        // 64 bytes
    #pragma unroll
    for (int j = 0; j < 8; ++j) {
        dst[j]      = h0[j];
        dst[8 + j]  = h1[j];
        dst[16 + j] = l0[j];
        dst[24 + j] = l1[j];
    }
    if (g < NCODES) {
        float s = 0.f;
        const float* e = emb + (size_t)g * DIM;
        #pragma unroll
        for (int d = 0; d < DIM; ++d) s += e[d] * e[d];
        nh[g] = -0.5f * s;
        counts[g] = 0;
    }
}

__global__ __launch_bounds__(256, 3) void vq_main(
        const float* __restrict__ x, const float* __restrict__ emb,
        const ushort* __restrict__ blob, const float* __restrict__ nh,
        float* __restrict__ out, int* __restrict__ counts, float* __restrict__ ssePart) {

    __shared__ __align__(16) ushort xh[MB * DIM];    // 8KB, swizzled bf16-hi of x
    __shared__ __align__(16) float  xf[MB][DIM];     // 16KB, exact f32 x
    __shared__ float2 part[MB][4];
    __shared__ int    rowIdx[MB];
    __shared__ float  wred[4];

    const int tid = threadIdx.x;
    const int lane = tid & 63;
    const int w = tid >> 6;             // wave 0..3: codes [w*16, w*16+16) of each chunk
    const int cB = w * 16;
    const int l15 = lane & 15, lhi = lane >> 4;
    const int rowBase = blockIdx.x * MB;

    // ---- stage x: f32 copy + bf16-hi (swizzled), once per block ----
    #pragma unroll
    for (int i = 0; i < 4; ++i) {
        int f = tid + 256 * i; int r = f >> 4, d4 = f & 15;
        float4 v = ((const float4*)x)[(size_t)(rowBase + r) * 16 + d4];
        *(float4*)&xf[r][d4 * 4] = v;
        ushort4 h = make_ushort4(f2bf(v.x), f2bf(v.y), f2bf(v.z), f2bf(v.w));
        *(ushort4*)((char*)xh + swz((uint)r, (uint)d4 * 8u)) = h;
    }
    __syncthreads();

    // ---- A fragments (x-hi) register-resident ----
    short8 afr[4][2];
    #pragma unroll
    for (int rm = 0; rm < 4; ++rm)
        #pragma unroll
        for (int ks = 0; ks < 2; ++ks)
            afr[rm][ks] = *(const short8*)((char*)xh + swz((uint)(rm * 16 + l15),
                                                           (uint)(ks * 64 + lhi * 16)));

    float b1[16];
    int   i1[16];
    #pragma unroll
    for (int s = 0; s < 16; ++s) { b1[s] = -FLT_MAX; i1[s] = 0; }

    const int codeBase = cB + l15;
    const ushort* bp = blob + ((size_t)w * 64 + lane) * 32;   // +8192 ushorts per chunk

    // prologue: load chunk 0
    short8 bc0 = *(const short8*)(bp + 0);
    short8 bc1 = *(const short8*)(bp + 8);
    short8 bc2 = *(const short8*)(bp + 16);
    short8 bc3 = *(const short8*)(bp + 24);
    float  nhv = nh[codeBase];

    for (int c = 0; c < NCHUNK; ++c) {
        // prefetch next chunk's B fragments + nh (T14: issue early, consume late)
        short8 bn0, bn1, bn2, bn3; float nhn = 0.f;
        if (c + 1 < NCHUNK) {
            const ushort* np_ = bp + (size_t)(c + 1) * 8192;
            bn0 = *(const short8*)(np_ + 0);
            bn1 = *(const short8*)(np_ + 8);
            bn2 = *(const short8*)(np_ + 16);
            bn3 = *(const short8*)(np_ + 24);
            nhn = nh[(c + 1) * 64 + codeBase];
        }

        // acc init = -0.5||e||^2 ; accumulate x.e  ->  acc = dot - hv = -dist
        floatx4 acc[4];
        #pragma unroll
        for (int rm = 0; rm < 4; ++rm) acc[rm] = (floatx4){nhv, nhv, nhv, nhv};

        #pragma unroll
        for (int rm = 0; rm < 4; ++rm) {
            acc[rm] = __builtin_amdgcn_mfma_f32_16x16x32_bf16(afr[rm][0], bc0, acc[rm], 0, 0, 0);
            acc[rm] = __builtin_amdgcn_mfma_f32_16x16x32_bf16(afr[rm][0], bc2, acc[rm], 0, 0, 0);
            acc[rm] = __builtin_amdgcn_mfma_f32_16x16x32_bf16(afr[rm][1], bc1, acc[rm], 0, 0, 0);
            acc[rm] = __builtin_amdgcn_mfma_f32_16x16x32_bf16(afr[rm][1], bc3, acc[rm], 0, 0, 0);
        }

        // top-1 (max of -dist); codes ascend per lane -> strict > keeps lowest index
        const int ccode = codeBase + c * 64;
        #pragma unroll
        for (int rm = 0; rm < 4; ++rm)
            #pragma unroll
            for (int j = 0; j < 4; ++j) {
                float d = acc[rm][j];
                int s = rm * 4 + j;
                if (d > b1[s]) { b1[s] = d; i1[s] = ccode; }
            }

        bc0 = bn0; bc1 = bn1; bc2 = bn2; bc3 = bn3; nhv = nhn;
    }

    // ---- cross-lane argmax merge within each 16-lane code group ----
    #pragma unroll
    for (int s = 0; s < 16; ++s) {
        float d1 = b1[s]; int j1 = i1[s];
        #pragma unroll
        for (int m = 1; m < 16; m <<= 1) {
            float od = __shfl_xor(d1, m);
            int   oj = __shfl_xor(j1, m);
            bool t = (od > d1) || (od == d1 && oj < j1);
            d1 = t ? od : d1;
            j1 = t ? oj : j1;
        }
        if (l15 == 0)
            part[(s >> 2) * 16 + lhi * 4 + (s & 3)][w] = make_float2(d1, __int_as_float(j1));
    }
    __syncthreads();

    // ---- per-row merge of 4 wave partials ----
    if (tid < MB) {
        float2 p = part[tid][0];
        float m1 = p.x; int j1 = __float_as_int(p.y);
        #pragma unroll
        for (int g = 1; g < 4; ++g) {
            float2 q = part[tid][g];
            int k1 = __float_as_int(q.y);
            bool t = (q.x > m1) || (q.x == m1 && k1 < j1);
            m1 = t ? q.x : m1;
            j1 = t ? k1 : j1;
        }
        rowIdx[tid] = j1;
        atomicAdd(&counts[j1], 1);
    }
    __syncthreads();

    // ---- epilogue: gather, straight-through out, SSE partial ----
    float myss = 0.f;
    #pragma unroll
    for (int i = 0; i < 4; ++i) {
        int f = tid + 256 * i; int r = f >> 4, d4 = f & 15;
        int idx = rowIdx[r];
        float4 q = ((const float4*)emb)[(size_t)idx * 16 + d4];
        float4 xv = *(const float4*)&xf[r][d4 * 4];
        float4 o;
        o.x = xv.x + (q.x - xv.x);
        o.y = xv.y + (q.y - xv.y);
        o.z = xv.z + (q.z - xv.z);
        o.w = xv.w + (q.w - xv.w);
        ((float4*)out)[(size_t)(rowBase + r) * 16 + d4] = o;
        float gx = o.x - xv.x, gy = o.y - xv.y, gz = o.z - xv.z, gw = o.w - xv.w;
        myss += gx * gx + gy * gy + gz * gz + gw * gw;
    }
    #pragma unroll
    for (int m = 32; m >= 1; m >>= 1) myss += __shfl_down(myss, m);
    if (lane == 0) wred[w] = myss;
    __syncthreads();
    if (tid == 0)
        ssePart[blockIdx.x] = wred[0] + wred[1] + wred[2] + wred[3];
}

__global__ void vq_final(const int* __restrict__ counts, const float* __restrict__ ssePart,
                         float* __restrict__ out) {
    __shared__ float pe[16], ps[16];
    int k = threadIdx.x;   // 1024 threads
    float p = (float)counts[k] * (1.0f / (float)N_ROWS);
    float ent = p * logf(p + 1e-10f);
    float sp = ssePart[k] + ssePart[k + 1024];
    #pragma unroll
    for (int m = 32; m >= 1; m >>= 1) {
        ent += __shfl_down(ent, m);
        sp  += __shfl_down(sp, m);
    }
    if ((k & 63) == 0) { pe[k >> 6] = ent; ps[k >> 6] = sp; }
    __syncthreads();
    if (k == 0) {
        float es = 0.f, ss = 0.f;
        #pragma unroll
        for (int w = 0; w < 16; ++w) { es += pe[w]; ss += ps[w]; }
        out[(size_t)N_ROWS * DIM]     = 1.25f * (ss / (float)(N_ROWS * DIM));
        out[(size_t)N_ROWS * DIM + 1] = expf(-es);
    }
}

extern "C" void kernel_launch(void* const* d_in, const int* in_sizes, int n_in,
                              void* d_out, int out_size, void* d_ws, size_t ws_size,
                              hipStream_t stream) {
    const float* x   = (const float*)d_in[0];
    const float* emb = (const float*)d_in[1];
    float*  out    = (float*)d_out;
    float*  nh     = (float*)d_ws;
    int*    counts = (int*)((char*)d_ws + 4096);
    float*  ssePrt = (float*)((char*)d_ws + 8192);
    ushort* blob   = (ushort*)((char*)d_ws + 16384);

    vq_prep<<<16, 256, 0, stream>>>(emb, nh, counts, blob);
    vq_main<<<N_ROWS / MB, 256, 0, stream>>>(x, emb, blob, nh, out, counts, ssePrt);
    vq_final<<<1, 1024, 0, stream>>>(counts, ssePrt, out);
}